// Round 4
// baseline (119.467 us; speedup 1.0000x reference)
//
#include <hip/hip_runtime.h>

// Problem constants
#define BTOT 65536
#define TST  28
#define BR   64      // batch rows per block
#define XPAD 40      // padded X row length (shorts): 32 used + 8 pad (bank skew)
#define HPAD 136     // padded H row length (shorts): 128 used + 8 pad (bank skew)

typedef __attribute__((ext_vector_type(8))) short bf16x8;
typedef __attribute__((ext_vector_type(4))) float f32x4;

__device__ __forceinline__ short f2bf(float f) {
    unsigned u = __float_as_uint(f);
    u += 0x7fff + ((u >> 16) & 1);   // round-to-nearest-even
    return (short)(u >> 16);
}

// Precompute Wx = W1 @ W2a (padded to 32x128, zero rows 28..31) and
// c = b2 + b1 @ W2a.  W2a = W2[:128], W2b = W2[128:].
__global__ void prep_kernel(const float* __restrict__ W1, const float* __restrict__ b1,
                            const float* __restrict__ W2, const float* __restrict__ b2,
                            float* __restrict__ wsWx, float* __restrict__ wsC) {
    int idx = blockIdx.x * 128 + threadIdx.x;
    if (idx < 32 * 128) {
        int k = idx >> 7, n = idx & 127;
        float s = 0.f;
        if (k < 28) {
            for (int j = 0; j < 128; ++j) s += W1[k * 128 + j] * W2[j * 128 + n];
        }
        wsWx[idx] = s;
    } else if (idx < 32 * 128 + 128) {
        int n = idx - 32 * 128;
        float s = b2[n];
        for (int j = 0; j < 128; ++j) s += b1[j] * W2[j * 128 + n];
        wsC[n] = s;
    }
}

__global__ __launch_bounds__(256) void rnn_kernel(
    const float* __restrict__ x, const float* __restrict__ W2,
    const float* __restrict__ W3, const float* __restrict__ b3,
    const float* __restrict__ wsWx, const float* __restrict__ wsC,
    float* __restrict__ out)
{
    __shared__ __align__(16) short Hs[2][BR][HPAD];   // hidden state, double-buffered, bf16
    __shared__ __align__(16) short Xs[BR][XPAD];      // current x tile, bf16

    const int tid  = threadIdx.x;
    const int wid  = tid >> 6;        // wave 0..3 -> owns output cols [wid*32, wid*32+32)
    const int lane = tid & 63;
    const int lr   = lane & 15;
    const int kh   = lane >> 4;       // 0..3
    const int r0   = blockIdx.x * BR;
    const int nb0  = wid * 32;

    // h0 = 0
    for (int i = tid; i < BR * HPAD; i += 256) (&Hs[0][0][0])[i] = 0;
    // zero X pad cols 28..31 (read by MFMA k=24..31)
    if (tid < BR) { Xs[tid][28] = 0; Xs[tid][29] = 0; Xs[tid][30] = 0; Xs[tid][31] = 0; }

    // Weight B-fragments, resident in registers for the whole time loop.
    // B-frag layout for 16x16x32: lane holds B[k=(lane>>4)*8+j][n=lane&15].
    bf16x8 bWx[2], bW2b[4][2];
    #pragma unroll
    for (int ct = 0; ct < 2; ++ct) {
        const int n = nb0 + ct * 16 + lr;
        bf16x8 v;
        #pragma unroll
        for (int j = 0; j < 8; ++j) v[j] = f2bf(wsWx[(kh * 8 + j) * 128 + n]);
        bWx[ct] = v;
        #pragma unroll
        for (int kk = 0; kk < 4; ++kk) {
            bf16x8 w;
            #pragma unroll
            for (int j = 0; j < 8; ++j)
                w[j] = f2bf(W2[(128 + kk * 32 + kh * 8 + j) * 128 + n]);
            bW2b[kk][ct] = w;
        }
    }
    const float cv0 = wsC[nb0 + lr];
    const float cv1 = wsC[nb0 + 16 + lr];

    // x staging assignment: 4 threads per row, 7 consecutive floats each
    const int xr = tid >> 2;
    const int xk = (tid & 3) * 7;
    const float* xbase = x + (size_t)(r0 + xr) * 784 + xk;

    float v[7], vn[7];
    #pragma unroll
    for (int i = 0; i < 7; ++i) { v[i] = xbase[i]; vn[i] = 0.f; }

    int cur = 0;
    for (int t = 0; t < TST; ++t) {
        // stage x_t -> LDS (bf16)
        #pragma unroll
        for (int i = 0; i < 7; ++i) Xs[xr][xk + i] = f2bf(v[i]);
        __syncthreads();

        // prefetch x_{t+1}; loads retire under the MFMAs below
        if (t + 1 < TST) {
            const float* xp = xbase + (t + 1) * 28;
            #pragma unroll
            for (int i = 0; i < 7; ++i) vn[i] = xp[i];
        }

        f32x4 acc[4][2];
        #pragma unroll
        for (int m = 0; m < 4; ++m) {
            acc[m][0] = (f32x4){cv0, cv0, cv0, cv0};
            acc[m][1] = (f32x4){cv1, cv1, cv1, cv1};
        }
        // x_t @ Wx   (one K=32 step, rows 28..31 zero)
        #pragma unroll
        for (int m = 0; m < 4; ++m) {
            bf16x8 aX = *(const bf16x8*)&Xs[m * 16 + lr][kh * 8];
            acc[m][0] = __builtin_amdgcn_mfma_f32_16x16x32_bf16(aX, bWx[0], acc[m][0], 0, 0, 0);
            acc[m][1] = __builtin_amdgcn_mfma_f32_16x16x32_bf16(aX, bWx[1], acc[m][1], 0, 0, 0);
        }
        // h @ W2b    (four K=32 steps)
        #pragma unroll
        for (int kk = 0; kk < 4; ++kk) {
            #pragma unroll
            for (int m = 0; m < 4; ++m) {
                bf16x8 aH = *(const bf16x8*)&Hs[cur][m * 16 + lr][kk * 32 + kh * 8];
                acc[m][0] = __builtin_amdgcn_mfma_f32_16x16x32_bf16(aH, bW2b[kk][0], acc[m][0], 0, 0, 0);
                acc[m][1] = __builtin_amdgcn_mfma_f32_16x16x32_bf16(aH, bW2b[kk][1], acc[m][1], 0, 0, 0);
            }
        }
        // relu + bf16 -> H[next]
        #pragma unroll
        for (int m = 0; m < 4; ++m)
            #pragma unroll
            for (int ct = 0; ct < 2; ++ct)
                #pragma unroll
                for (int j = 0; j < 4; ++j) {
                    float h = acc[m][ct][j];
                    h = h > 0.f ? h : 0.f;
                    Hs[cur ^ 1][m * 16 + kh * 4 + j][nb0 + ct * 16 + lr] = f2bf(h);
                }
        __syncthreads();
        cur ^= 1;
        #pragma unroll
        for (int i = 0; i < 7; ++i) v[i] = vn[i];
    }

    // out = h_final @ W3 + b3 ; wave w computes row tile w (16 rows x 16 cols, 10 valid)
    bf16x8 bW3[4];
    #pragma unroll
    for (int kk = 0; kk < 4; ++kk) {
        bf16x8 w;
        #pragma unroll
        for (int j = 0; j < 8; ++j) {
            int k = kk * 32 + kh * 8 + j;
            w[j] = (lr < 10) ? f2bf(W3[k * 10 + lr]) : (short)0;
        }
        bW3[kk] = w;
    }
    const float bv = (lr < 10) ? b3[lr] : 0.f;
    f32x4 accO = (f32x4){bv, bv, bv, bv};
    #pragma unroll
    for (int kk = 0; kk < 4; ++kk) {
        bf16x8 aH = *(const bf16x8*)&Hs[cur][wid * 16 + lr][kk * 32 + kh * 8];
        accO = __builtin_amdgcn_mfma_f32_16x16x32_bf16(aH, bW3[kk], accO, 0, 0, 0);
    }
    if (lr < 10) {
        #pragma unroll
        for (int j = 0; j < 4; ++j)
            out[(size_t)(r0 + wid * 16 + kh * 4 + j) * 10 + lr] = accO[j];
    }
}

extern "C" void kernel_launch(void* const* d_in, const int* in_sizes, int n_in,
                              void* d_out, int out_size, void* d_ws, size_t ws_size,
                              hipStream_t stream) {
    const float* x  = (const float*)d_in[0];
    const float* W1 = (const float*)d_in[1];
    const float* b1 = (const float*)d_in[2];
    const float* W2 = (const float*)d_in[3];
    const float* b2 = (const float*)d_in[4];
    const float* W3 = (const float*)d_in[5];
    const float* b3 = (const float*)d_in[6];
    float* out  = (float*)d_out;
    float* wsWx = (float*)d_ws;            // 32*128 fp32
    float* wsC  = wsWx + 32 * 128;         // 128 fp32

    prep_kernel<<<33, 128, 0, stream>>>(W1, b1, W2, b2, wsWx, wsC);
    rnn_kernel<<<BTOT / BR, 256, 0, stream>>>(x, W2, W3, b3, wsWx, wsC, out);
}